// Round 9
// baseline (615.227 us; speedup 1.0000x reference)
//
#include <hip/hip_runtime.h>
#include <hip/hip_bf16.h>

// ---------------------------------------------------------------------------
// SparseLaneAttention on MI355X (gfx950) — round 9.
// r8 post-mortem: layer kernel 82us, still latency-bound: grid 1024 x 4 waves
// caps at 16 waves/CU (39% occ), and random gathers thrash per-XCD L2 (FETCH
// 27.7MB = 6.6x feat). Fix: 512-thread blocks over the same 16 rows — two
// gather groups (type 2i+g per iteration, 4 slabs pairwise double-buffered),
// 8 waves x 1 column-block MFMA. 32 waves/CU theoretical, 7 barriers vs 14.
// build_first4+build_cntpack fused into build_aux.
// ---------------------------------------------------------------------------

typedef __bf16 bf16_t;
typedef __attribute__((ext_vector_type(8))) __bf16 bf16x8;
typedef __attribute__((ext_vector_type(4))) __bf16 bf16x4;
typedef __attribute__((ext_vector_type(4))) float f32x4;
typedef unsigned long long u64;

#define MROWS 16384   // B*N
#define DDIM  128
#define EEDGE 32768
#define NSEQ  1024
#define NBATCH 16
#define CAP   16
#define NTYPE 14
#define NKEY  (NTYPE * MROWS)
#define OVMAX 4096
#define NCHUNK 4      // flash KV split

// ---------------------------------------------------------------------------
// Multi-segment f32 -> bf16 conversion
// ---------------------------------------------------------------------------
struct CvtArgs {
    const float* src[6];
    bf16_t* dst[6];
    int n4[6];
};

__global__ __launch_bounds__(256) void cvt_multi(CvtArgs a, int total4) {
    int i = blockIdx.x * 256 + threadIdx.x;
    if (i >= total4) return;
    int k = 0, base = 0;
    while (i - base >= a.n4[k]) { base += a.n4[k]; ++k; }
    int j = i - base;
    float4 v = reinterpret_cast<const float4*>(a.src[k])[j];
    bf16x4 o = { (bf16_t)v.x, (bf16_t)v.y, (bf16_t)v.z, (bf16_t)v.w };
    reinterpret_cast<bf16x4*>(a.dst[k])[j] = o;
}

// ---------------------------------------------------------------------------
// wcat[layer][15][128][128] bf16; slots 0..5 pre, 6..11 suc, 12 left,
// 13 right, 14 ctr.
// ---------------------------------------------------------------------------
__global__ __launch_bounds__(256) void cvt_wcat(
    const float* __restrict__ W_ctr, const float* __restrict__ W_pre,
    const float* __restrict__ W_suc, const float* __restrict__ W_left,
    const float* __restrict__ W_right, bf16_t* __restrict__ wcat)
{
    int tid = blockIdx.x * 256 + threadIdx.x;
    int idx = tid * 4;
    if (idx >= 4 * 15 * 16384) return;
    const int PER_I = 15 * 16384;
    int i = idx / PER_I, rem = idx % PER_I;
    int slot = rem / 16384, k = rem % 16384;
    const float* src;
    if (slot < 6)       src = W_pre  + ((size_t)(i * 6 + slot) * 16384 + k);
    else if (slot < 12) src = W_suc  + ((size_t)(i * 6 + slot - 6) * 16384 + k);
    else if (slot == 12) src = W_left  + ((size_t)i * 16384 + k);
    else if (slot == 13) src = W_right + ((size_t)i * 16384 + k);
    else                 src = W_ctr   + ((size_t)i * 16384 + k);
    float4 v = *reinterpret_cast<const float4*>(src);
    bf16x4 o = { (bf16_t)v.x, (bf16_t)v.y, (bf16_t)v.z, (bf16_t)v.w };
    *reinterpret_cast<bf16x4*>(wcat + idx) = o;
}

// ---------------------------------------------------------------------------
// Build CSR (once per call; indices are call-invariant).
// ---------------------------------------------------------------------------
__global__ __launch_bounds__(256) void build_csr(
    const int* __restrict__ pre_u, const int* __restrict__ pre_v,
    const int* __restrict__ suc_u, const int* __restrict__ suc_v,
    const int* __restrict__ left_u, const int* __restrict__ left_v,
    const int* __restrict__ right_u, const int* __restrict__ right_v,
    unsigned* __restrict__ cnt, int* __restrict__ csr,
    unsigned* __restrict__ ovcnt, int* __restrict__ ovlist)
{
    int tid = blockIdx.x * 256 + threadIdx.x;
    int t = tid >> 15, e = tid & (EEDGE - 1);
    const int* ua; const int* va;
    if (t < 6)        { ua = pre_u + t * EEDGE;       va = pre_v + t * EEDGE; }
    else if (t < 12)  { ua = suc_u + (t - 6) * EEDGE; va = suc_v + (t - 6) * EEDGE; }
    else if (t == 12) { ua = left_u;  va = left_v; }
    else              { ua = right_u; va = right_v; }
    int u = ua[e], v = va[e];
    int key = t * MROWS + u;
    unsigned slot = atomicAdd(&cnt[key], 1u);
    if (slot < CAP) csr[key * CAP + slot] = v;
    else {
        unsigned o = atomicAdd(ovcnt, 1u);
        if (o < OVMAX) { ovlist[o * 2] = key; ovlist[o * 2 + 1] = v; }
    }
}

// ---------------------------------------------------------------------------
// Fused aux build: first4 (sentinel-padded) for all keys + nibble-packed
// per-row counts (14 x 4 bits; nibble==15 -> consult cnt).
// ---------------------------------------------------------------------------
__global__ __launch_bounds__(256) void build_aux(
    const unsigned* __restrict__ cnt, const int* __restrict__ csr,
    int4* __restrict__ first4, u64* __restrict__ cnt_pack)
{
    int idx = blockIdx.x * 256 + threadIdx.x;
    if (idx < NKEY) {
        unsigned c = cnt[idx];
        const int* p = csr + (size_t)idx * CAP;
        int4 q;
        q.x = (c > 0) ? p[0] : MROWS;
        q.y = (c > 1) ? p[1] : MROWS;
        q.z = (c > 2) ? p[2] : MROWS;
        q.w = (c > 3) ? p[3] : MROWS;
        first4[idx] = q;
    } else if (idx < NKEY + MROWS) {
        int row = idx - NKEY;
        u64 cc = 0;
#pragma unroll
        for (int t = 0; t < NTYPE; ++t) {
            unsigned c = cnt[t * MROWS + row];
            if (c > 15u) c = 15u;
            cc |= (u64)c << (4 * t);
        }
        cnt_pack[row] = cc;
    }
}

// ---------------------------------------------------------------------------
// QKV projection; q/k outputs staged through LDS for vectorized stores.
// ---------------------------------------------------------------------------
__global__ __launch_bounds__(256) void qkv_gemm(
    const bf16_t* __restrict__ ctrs_bf, const bf16_t* __restrict__ feats_bf,
    const bf16_t* __restrict__ wq, const bf16_t* __restrict__ wk, const bf16_t* __restrict__ wv,
    bf16_t* __restrict__ q_out, bf16_t* __restrict__ k_out, bf16_t* __restrict__ vT_out)
{
    __shared__ bf16_t stg[64][132];
    const int which = blockIdx.y;
    const bf16_t* x = (which == 0) ? ctrs_bf : feats_bf;
    const bf16_t* w = (which == 0) ? wq : (which == 1) ? wk : wv;
    const int lane = threadIdx.x & 63, wave = threadIdx.x >> 6;
    const int li = lane & 15, kg = lane >> 4;
    const int row0 = blockIdx.x * 64 + wave * 16;

    bf16x8 a[4];
#pragma unroll
    for (int kk = 0; kk < 4; ++kk)
        a[kk] = *reinterpret_cast<const bf16x8*>(x + (size_t)(row0 + li) * DDIM + kk * 32 + kg * 8);

    f32x4 acc[8];
#pragma unroll
    for (int t = 0; t < 8; ++t) {
        f32x4 c = {0.f, 0.f, 0.f, 0.f};
#pragma unroll
        for (int kk = 0; kk < 4; ++kk) {
            bf16x8 b = *reinterpret_cast<const bf16x8*>(w + (size_t)(t * 16 + li) * DDIM + kk * 32 + kg * 8);
            c = __builtin_amdgcn_mfma_f32_16x16x32_bf16(a[kk], b, c, 0, 0, 0);
        }
        acc[t] = c;
    }

    if (which < 2) {
        bf16_t* out = (which == 0) ? q_out : k_out;
#pragma unroll
        for (int t = 0; t < 8; ++t) {
            int c = t * 16 + li;
#pragma unroll
            for (int r = 0; r < 4; ++r)
                stg[wave * 16 + kg * 4 + r][c] = (bf16_t)acc[t][r];
        }
        __syncthreads();
        const int rr = threadIdx.x >> 2, seg = (threadIdx.x & 3) * 32;
#pragma unroll
        for (int p = 0; p < 4; ++p) {
            bf16x8 v = *reinterpret_cast<const bf16x8*>(&stg[rr][seg + p * 8]);
            *reinterpret_cast<bf16x8*>(out + (size_t)(blockIdx.x * 64 + rr) * DDIM + seg + p * 8) = v;
        }
    } else {
        const int bb = row0 >> 10;
        const int jb = (row0 & 1023) + kg * 4;
#pragma unroll
        for (int t = 0; t < 8; ++t) {
            int c = t * 16 + li;
            bf16x4 pk = { (bf16_t)acc[t][0], (bf16_t)acc[t][1], (bf16_t)acc[t][2], (bf16_t)acc[t][3] };
            *reinterpret_cast<bf16x4*>(vT_out + ((size_t)bb * 128 + c) * NSEQ + jb) = pk;
        }
    }
}

// ---------------------------------------------------------------------------
// Flash attention, KV-split (unchanged).
// ---------------------------------------------------------------------------
__global__ __launch_bounds__(256) void flash_attn(
    const bf16_t* __restrict__ q, const bf16_t* __restrict__ k,
    const bf16_t* __restrict__ vT,
    float* __restrict__ pO, float* __restrict__ pm, float* __restrict__ pl)
{
    const int lane = threadIdx.x & 63, wave = threadIdx.x >> 6;
    const int li = lane & 15, kg = lane >> 4;
    const int b = blockIdx.y;
    const int chunk = blockIdx.z;
    const int i0 = blockIdx.x * 64 + wave * 16;

    __shared__ bf16_t p_lds[4][16][48];

    bf16x8 qf[4];
#pragma unroll
    for (int kk = 0; kk < 4; ++kk)
        qf[kk] = *reinterpret_cast<const bf16x8*>(q + ((size_t)b * NSEQ + i0 + li) * DDIM + kk * 32 + kg * 8);

    float m_run = -1e30f, l_run = 0.f;
    f32x4 o[8];
#pragma unroll
    for (int t = 0; t < 8; ++t) o[t] = f32x4{0.f, 0.f, 0.f, 0.f};

    const float nf = 0.08838834764831845f;
    const int jlo = chunk * (NSEQ / NCHUNK), jhi = jlo + NSEQ / NCHUNK;

    for (int j0 = jlo; j0 < jhi; j0 += 32) {
        f32x4 s[2];
#pragma unroll
        for (int sub = 0; sub < 2; ++sub) {
            f32x4 c = {0.f, 0.f, 0.f, 0.f};
#pragma unroll
            for (int kk = 0; kk < 4; ++kk) {
                bf16x8 a = *reinterpret_cast<const bf16x8*>(
                    k + ((size_t)b * NSEQ + j0 + sub * 16 + li) * DDIM + kk * 32 + kg * 8);
                c = __builtin_amdgcn_mfma_f32_16x16x32_bf16(a, qf[kk], c, 0, 0, 0);
            }
            s[sub] = c;
        }
        float smax = -1e30f;
#pragma unroll
        for (int sub = 0; sub < 2; ++sub)
#pragma unroll
            for (int r = 0; r < 4; ++r) { s[sub][r] *= nf; smax = fmaxf(smax, s[sub][r]); }
        smax = fmaxf(smax, __shfl_xor(smax, 16));
        smax = fmaxf(smax, __shfl_xor(smax, 32));
        float m_new = fmaxf(m_run, smax);
        float alpha = __expf(m_run - m_new);
        float psum = 0.f;
#pragma unroll
        for (int sub = 0; sub < 2; ++sub) {
            bf16x4 pk;
#pragma unroll
            for (int r = 0; r < 4; ++r) {
                float p = __expf(s[sub][r] - m_new);
                psum += p;
                pk[r] = (bf16_t)p;
            }
            *reinterpret_cast<bf16x4*>(&p_lds[wave][li][sub * 16 + kg * 4]) = pk;
        }
        psum += __shfl_xor(psum, 16);
        psum += __shfl_xor(psum, 32);
        l_run = l_run * alpha + psum;
        m_run = m_new;

        float al[4];
#pragma unroll
        for (int r = 0; r < 4; ++r) al[r] = __shfl(alpha, kg * 4 + r);

        asm volatile("s_waitcnt lgkmcnt(0)" ::: "memory");
        __builtin_amdgcn_sched_barrier(0);

        bf16x8 pa = *reinterpret_cast<const bf16x8*>(&p_lds[wave][li][kg * 8]);

#pragma unroll
        for (int t = 0; t < 8; ++t)
#pragma unroll
            for (int r = 0; r < 4; ++r) o[t][r] *= al[r];

#pragma unroll
        for (int t = 0; t < 8; ++t) {
            bf16x8 vb = *reinterpret_cast<const bf16x8*>(
                vT + ((size_t)b * 128 + t * 16 + li) * NSEQ + j0 + kg * 8);
            o[t] = __builtin_amdgcn_mfma_f32_16x16x32_bf16(pa, vb, o[t], 0, 0, 0);
        }
    }

#pragma unroll
    for (int t = 0; t < 8; ++t) {
        int c = t * 16 + li;
#pragma unroll
        for (int r = 0; r < 4; ++r) {
            size_t m = (size_t)b * NSEQ + i0 + kg * 4 + r;
            pO[((size_t)chunk * MROWS + m) * DDIM + c] = o[t][r];
        }
    }
    float m_r[4], l_r[4];
#pragma unroll
    for (int r = 0; r < 4; ++r) { m_r[r] = __shfl(m_run, kg * 4 + r); l_r[r] = __shfl(l_run, kg * 4 + r); }
    if (li == 0) {
#pragma unroll
        for (int r = 0; r < 4; ++r) {
            size_t m = (size_t)b * NSEQ + i0 + kg * 4 + r;
            pm[(size_t)chunk * MROWS + m] = m_r[r];
            pl[(size_t)chunk * MROWS + m] = l_r[r];
        }
    }
}

// ---------------------------------------------------------------------------
// Combine chunk partials (exact) -> feat = feats + att.
// ---------------------------------------------------------------------------
__global__ __launch_bounds__(256) void attn_combine(
    const float* __restrict__ pO, const float* __restrict__ pm, const float* __restrict__ pl,
    const float* __restrict__ feats, bf16_t* __restrict__ feat_bf, float* __restrict__ res)
{
    int idx = blockIdx.x * 256 + threadIdx.x;
    int row = idx >> 7;
    float mx = -1e30f;
#pragma unroll
    for (int c = 0; c < NCHUNK; ++c) mx = fmaxf(mx, pm[(size_t)c * MROWS + row]);
    float num = 0.f, den = 0.f;
#pragma unroll
    for (int c = 0; c < NCHUNK; ++c) {
        float wgt = __expf(pm[(size_t)c * MROWS + row] - mx);
        den += wgt * pl[(size_t)c * MROWS + row];
        num += wgt * pO[((size_t)c * MROWS + row) * DDIM + (idx & 127)];
    }
    float f = feats[idx] + num / den;
    feat_bf[idx] = (bf16_t)f;
    res[idx] = f;
}

// ---------------------------------------------------------------------------
// Fused layer kernel v5.  Block = 16 dest rows, 512 threads (8 waves).
// Gather: two groups (grp = tid>>8); group g gathers type 2i+g per iteration
// into slab[(i&1)*2+g] (4 slabs, pairwise double-buffered). MFMA: 8 waves x
// 1 column-block each; pair (2i,2i+1) consumed per iteration; ctr slot (14)
// in prologue from fin. 7 barriers. Tail: GN1+ReLU -> ctr2 MFMA -> GN2+res.
// LDS ~30KB -> occupancy grid-capped at 4 blocks x 8 waves = 32 waves/CU.
// ---------------------------------------------------------------------------
__global__ __launch_bounds__(512) void layer_fused5(
    const bf16_t* __restrict__ fin,          // (MROWS+1) rows; row MROWS = 0
    const unsigned* __restrict__ cnt, const int* __restrict__ csr,
    const int4* __restrict__ first4, const u64* __restrict__ cnt_pack,
    const unsigned* __restrict__ ovcnt, const int* __restrict__ ovlist,
    const bf16_t* __restrict__ wcat_l, const bf16_t* __restrict__ wctr2_l,
    const float* __restrict__ g1, const float* __restrict__ b1,
    const float* __restrict__ g2, const float* __restrict__ b2,
    float* __restrict__ res, bf16_t* __restrict__ fout, float* __restrict__ out_f32)
{
    __shared__ bf16_t slab[4][16][136];   // 4 x 4352 B
    __shared__ float  t2[16][132];        // 8448 B
    __shared__ bf16_t yA[16][136];        // 4352 B
    const int tid = threadIdx.x;
    const int grp = tid >> 8;                    // gather group 0/1
    const int r = (tid >> 4) & 15, lp = tid & 15;
    const int row0 = blockIdx.x * 16;
    const int row = row0 + r;
    const int ch = lp * 8;
    const int lane = tid & 63, w = tid >> 6;     // wave 0..7
    const int li = lane & 15, kg = lane >> 4;

    const u64 cc = cnt_pack[row];

    auto gather_t = [&](int t, float* s) {
        int4 qd = first4[t * MROWS + row];
        bf16x8 x0 = *reinterpret_cast<const bf16x8*>(fin + (size_t)qd.x * DDIM + ch);
        bf16x8 x1 = *reinterpret_cast<const bf16x8*>(fin + (size_t)qd.y * DDIM + ch);
        bf16x8 x2 = *reinterpret_cast<const bf16x8*>(fin + (size_t)qd.z * DDIM + ch);
        bf16x8 x3 = *reinterpret_cast<const bf16x8*>(fin + (size_t)qd.w * DDIM + ch);
#pragma unroll
        for (int z = 0; z < 8; ++z)
            s[z] = ((float)x0[z] + (float)x1[z]) + ((float)x2[z] + (float)x3[z]);
        int nib = (int)((cc >> (4 * t)) & 15u);
        if (nib > 4) {                                   // rare
            const int key = t * MROWS + row;
            unsigned craw = (nib == 15) ? cnt[key] : (unsigned)nib;
            int c = (int)(craw < CAP ? craw : CAP);
            for (int j = 4; j < c; ++j) {
                bf16x8 x = *reinterpret_cast<const bf16x8*>(fin + (size_t)csr[(size_t)key * CAP + j] * DDIM + ch);
#pragma unroll
                for (int z = 0; z < 8; ++z) s[z] += (float)x[z];
            }
            if (craw > CAP) {                            // ~never
                unsigned no = *ovcnt; if (no > OVMAX) no = OVMAX;
                for (unsigned o = 0; o < no; ++o) {
                    if (ovlist[o * 2] == key) {
                        bf16x8 x = *reinterpret_cast<const bf16x8*>(fin + (size_t)ovlist[o * 2 + 1] * DDIM + ch);
#pragma unroll
                        for (int z = 0; z < 8; ++z) s[z] += (float)x[z];
                    }
                }
            }
        }
    };

    f32x4 acc = {0.f, 0.f, 0.f, 0.f};            // column block w

    // prologue: gather type grp -> slab[grp]; ctr slot (14) MFMA meanwhile
    {
        float s[8];
        gather_t(grp, s);
        bf16x8 af[4];
#pragma unroll
        for (int kk = 0; kk < 4; ++kk)
            af[kk] = *reinterpret_cast<const bf16x8*>(fin + (size_t)(row0 + li) * DDIM + kk * 32 + kg * 8);
        const bf16_t* wt = wcat_l + (size_t)14 * 16384;
#pragma unroll
        for (int kk = 0; kk < 4; ++kk) {
            bf16x8 b = *reinterpret_cast<const bf16x8*>(wt + (size_t)(w * 16 + li) * DDIM + kk * 32 + kg * 8);
            acc = __builtin_amdgcn_mfma_f32_16x16x32_bf16(af[kk], b, acc, 0, 0, 0);
        }
        bf16x8 av;
#pragma unroll
        for (int z = 0; z < 8; ++z) av[z] = (bf16_t)s[z];
        *reinterpret_cast<bf16x8*>(&slab[grp][r][ch]) = av;
    }
    __syncthreads();

    for (int i = 0; i < 7; ++i) {
        float s2[8];
        const bool more = (i < 6);
        if (more) gather_t(2 * (i + 1) + grp, s2);       // overlaps MFMA below

        const int sb = (i & 1) * 2;
        bf16x8 a0[4], a1[4];
#pragma unroll
        for (int kk = 0; kk < 4; ++kk) {
            a0[kk] = *reinterpret_cast<const bf16x8*>(&slab[sb][li][kk * 32 + kg * 8]);
            a1[kk] = *reinterpret_cast<const bf16x8*>(&slab[sb + 1][li][kk * 32 + kg * 8]);
        }
        const bf16_t* wt0 = wcat_l + (size_t)(2 * i) * 16384;
        const bf16_t* wt1 = wcat_l + (size_t)(2 * i + 1) * 16384;
#pragma unroll
        for (int kk = 0; kk < 4; ++kk) {
            bf16x8 b0 = *reinterpret_cast<const bf16x8*>(wt0 + (size_t)(w * 16 + li) * DDIM + kk * 32 + kg * 8);
            acc = __builtin_amdgcn_mfma_f32_16x16x32_bf16(a0[kk], b0, acc, 0, 0, 0);
            bf16x8 b1 = *reinterpret_cast<const bf16x8*>(wt1 + (size_t)(w * 16 + li) * DDIM + kk * 32 + kg * 8);
            acc = __builtin_amdgcn_mfma_f32_16x16x32_bf16(a1[kk], b1, acc, 0, 0, 0);
        }

        if (more) {
            bf16x8 av;
#pragma unroll
            for (int z = 0; z < 8; ++z) av[z] = (bf16_t)s2[z];
            *reinterpret_cast<bf16x8*>(&slab[((i + 1) & 1) * 2 + grp][r][ch]) = av;
        }
        __syncthreads();
    }

#pragma unroll
    for (int rr = 0; rr < 4; ++rr)
        t2[kg * 4 + rr][w * 16 + li] = acc[rr];
    __syncthreads();

    // ---- GN1 + ReLU -> yA (first 256 threads; 8ch each) ----
    if (tid < 256) {
        float s[8];
#pragma unroll
        for (int z = 0; z < 8; ++z) s[z] = t2[r][ch + z];
        float sm = 0.f, sq = 0.f;
#pragma unroll
        for (int z = 0; z < 8; ++z) { sm += s[z]; sq += s[z] * s[z]; }
#pragma unroll
        for (int off = 1; off < 16; off <<= 1) { sm += __shfl_xor(sm, off); sq += __shfl_xor(sq, off); }
        float mu = sm * (1.f / 128.f);
        float var = sq * (1.f / 128.f) - mu * mu;
        float rstd = rsqrtf(var + 1e-5f);
        bf16x8 yv;
#pragma unroll
        for (int z = 0; z < 8; ++z) {
            float y = fmaxf((s[z] - mu) * rstd * g1[ch + z] + b1[ch + z], 0.f);
            yv[z] = (bf16_t)y;
        }
        *reinterpret_cast<bf16x8*>(&yA[r][ch]) = yv;
    }
    __syncthreads();

    // ---- ctr2 GEMM from yA (8 waves x 1 column block) ----
    {
        bf16x8 a2[4];
#pragma unroll
        for (int kk = 0; kk < 4; ++kk)
            a2[kk] = *reinterpret_cast<const bf16x8*>(&yA[li][kk * 32 + kg * 8]);
        f32x4 c2 = {0.f, 0.f, 0.f, 0.f};
#pragma unroll
        for (int kk = 0; kk < 4; ++kk) {
            bf16x8 b = *reinterpret_cast<const bf16x8*>(wctr2_l + (size_t)(w * 16 + li) * DDIM + kk * 32 + kg * 8);
            c2 = __builtin_amdgcn_mfma_f32_16x16x32_bf16(a2[kk], b, c2, 0, 0, 0);
        }
        __syncthreads();   // yA reads done before t2 overwrite? (t2 distinct; sync for t2 reuse below)
#pragma unroll
        for (int rr = 0; rr < 4; ++rr)
            t2[kg * 4 + rr][w * 16 + li] = c2[rr];
    }
    __syncthreads();

    // ---- GN2 + residual + ReLU (first 256 threads) ----
    if (tid < 256) {
        float v[8];
#pragma unroll
        for (int z = 0; z < 8; ++z) v[z] = t2[r][ch + z];
        float sm = 0.f, sq = 0.f;
#pragma unroll
        for (int z = 0; z < 8; ++z) { sm += v[z]; sq += v[z] * v[z]; }
#pragma unroll
        for (int off = 1; off < 16; off <<= 1) { sm += __shfl_xor(sm, off); sq += __shfl_xor(sq, off); }
        float mu = sm * (1.f / 128.f);
        float var = sq * (1.f / 128.f) - mu * mu;
        float rstd = rsqrtf(var + 1e-5f);

        size_t base = (size_t)row * DDIM + ch;
        float rv[8];
        *reinterpret_cast<float4*>(&rv[0]) = *reinterpret_cast<const float4*>(res + base);
        *reinterpret_cast<float4*>(&rv[4]) = *reinterpret_cast<const float4*>(res + base + 4);
        bf16x8 fo;
#pragma unroll
        for (int z = 0; z < 8; ++z) {
            float y = (v[z] - mu) * rstd * g2[ch + z] + b2[ch + z];
            float f = fmaxf(y + rv[z], 0.f);
            rv[z] = f;
            fo[z] = (bf16_t)f;
        }
        *reinterpret_cast<float4*>(res + base) = *reinterpret_cast<float4*>(&rv[0]);
        *reinterpret_cast<float4*>(res + base + 4) = *reinterpret_cast<float4*>(&rv[4]);
        *reinterpret_cast<bf16x8*>(fout + base) = fo;
        if (out_f32) {
            *reinterpret_cast<float4*>(out_f32 + base) = *reinterpret_cast<float4*>(&rv[0]);
            *reinterpret_cast<float4*>(out_f32 + base + 4) = *reinterpret_cast<float4*>(&rv[4]);
        }
    }
}

// ---------------------------------------------------------------------------
// Host launch
// ---------------------------------------------------------------------------
extern "C" void kernel_launch(void* const* d_in, const int* in_sizes, int n_in,
                              void* d_out, int out_size, void* d_ws, size_t ws_size,
                              hipStream_t stream) {
    const float* ctrs   = (const float*)d_in[0];
    const float* feats  = (const float*)d_in[1];
    const float* Wq     = (const float*)d_in[2];
    const float* Wk     = (const float*)d_in[3];
    const float* Wv     = (const float*)d_in[4];
    const float* W_ctr  = (const float*)d_in[5];
    const float* W_pre  = (const float*)d_in[6];
    const float* W_suc  = (const float*)d_in[7];
    const float* W_left = (const float*)d_in[8];
    const float* W_right= (const float*)d_in[9];
    const float* W_ctr2 = (const float*)d_in[10];
    const float* gn_g   = (const float*)d_in[11];
    const float* gn_b   = (const float*)d_in[12];
    const float* gn2_g  = (const float*)d_in[13];
    const float* gn2_b  = (const float*)d_in[14];
    const int* pre_u    = (const int*)d_in[15];
    const int* pre_v    = (const int*)d_in[16];
    const int* suc_u    = (const int*)d_in[17];
    const int* suc_v    = (const int*)d_in[18];
    const int* left_u   = (const int*)d_in[19];
    const int* left_v   = (const int*)d_in[20];
    const int* right_u  = (const int*)d_in[21];
    const int* right_v  = (const int*)d_in[22];
    (void)in_sizes; (void)n_in; (void)out_size; (void)ws_size;

    size_t off = 0;
    auto alloc = [&](size_t bytes) -> void* {
        void* p = (char*)d_ws + off;
        off += (bytes + 255) & ~(size_t)255;
        return p;
    };
    // persistent region
    bf16_t* wq_b    = (bf16_t*)alloc(16384 * 2);
    bf16_t* wk_b    = (bf16_t*)alloc(16384 * 2);
    bf16_t* wv_b    = (bf16_t*)alloc(16384 * 2);
    bf16_t* wctr2_b = (bf16_t*)alloc(65536 * 2);
    bf16_t* wcat    = (bf16_t*)alloc((size_t)4 * 15 * 16384 * 2);
    bf16_t* featA   = (bf16_t*)alloc((size_t)(MROWS + 1) * DDIM * 2);   // +1 zero row
    bf16_t* featB   = (bf16_t*)alloc((size_t)(MROWS + 1) * DDIM * 2);   // +1 zero row
    float*  res_f   = (float*)alloc((size_t)MROWS * DDIM * 4);
    unsigned* cnt   = (unsigned*)alloc((size_t)NKEY * 4);
    unsigned* ovcnt = (unsigned*)alloc(256);
    int*    csr     = (int*)alloc((size_t)NKEY * CAP * 4);
    int*    ovlist  = (int*)alloc((size_t)OVMAX * 2 * 4);
    int4*   first4  = (int4*)alloc((size_t)NKEY * 16);
    u64*    cnt_pack= (u64*)alloc((size_t)MROWS * 8);

    // attention-phase temporaries
    bf16_t* ctrs_b  = (bf16_t*)alloc((size_t)MROWS * DDIM * 2);
    bf16_t* feats_b = (bf16_t*)alloc((size_t)MROWS * DDIM * 2);
    bf16_t* q_b     = (bf16_t*)alloc((size_t)MROWS * DDIM * 2);
    bf16_t* k_b     = (bf16_t*)alloc((size_t)MROWS * DDIM * 2);
    bf16_t* vT_b    = (bf16_t*)alloc((size_t)MROWS * DDIM * 2);
    float*  pm      = (float*)alloc((size_t)NCHUNK * MROWS * 4);
    float*  pl      = (float*)alloc((size_t)NCHUNK * MROWS * 4);
    float*  pO      = (float*)alloc((size_t)NCHUNK * MROWS * DDIM * 4);

    // --- preprocessing ---
    hipMemsetAsync(cnt, 0, (size_t)NKEY * 4 + 256, stream);            // cnt + ovcnt
    hipMemsetAsync(featA + (size_t)MROWS * DDIM, 0, DDIM * 2, stream); // zero sentinel rows
    hipMemsetAsync(featB + (size_t)MROWS * DDIM, 0, DDIM * 2, stream);

    CvtArgs ca;
    ca.src[0] = ctrs;   ca.dst[0] = ctrs_b;  ca.n4[0] = MROWS * DDIM / 4;
    ca.src[1] = feats;  ca.dst[1] = feats_b; ca.n4[1] = MROWS * DDIM / 4;
    ca.src[2] = Wq;     ca.dst[2] = wq_b;    ca.n4[2] = 16384 / 4;
    ca.src[3] = Wk;     ca.dst[3] = wk_b;    ca.n4[3] = 16384 / 4;
    ca.src[4] = Wv;     ca.dst[4] = wv_b;    ca.n4[4] = 16384 / 4;
    ca.src[5] = W_ctr2; ca.dst[5] = wctr2_b; ca.n4[5] = 65536 / 4;
    int total4 = (2 * MROWS * DDIM + 3 * 16384 + 65536) / 4;
    cvt_multi<<<dim3((total4 + 255) / 256), dim3(256), 0, stream>>>(ca, total4);

    cvt_wcat<<<dim3((4 * 15 * 16384 / 4 + 255) / 256), dim3(256), 0, stream>>>(
        W_ctr, W_pre, W_suc, W_left, W_right, wcat);

    build_csr<<<dim3(NTYPE * EEDGE / 256), dim3(256), 0, stream>>>(
        pre_u, pre_v, suc_u, suc_v, left_u, left_v, right_u, right_v,
        cnt, csr, ovcnt, ovlist);

    build_aux<<<dim3((NKEY + MROWS + 255) / 256), dim3(256), 0, stream>>>(
        cnt, csr, first4, cnt_pack);

    // --- attention ---
    qkv_gemm<<<dim3(MROWS / 64, 3), dim3(256), 0, stream>>>(
        ctrs_b, feats_b, wq_b, wk_b, wv_b, q_b, k_b, vT_b);

    flash_attn<<<dim3(NSEQ / 64, NBATCH, NCHUNK), dim3(256), 0, stream>>>(
        q_b, k_b, vT_b, pO, pm, pl);

    attn_combine<<<dim3(MROWS * DDIM / 256), dim3(256), 0, stream>>>(
        pO, pm, pl, feats, featA, res_f);

    // --- fusion layers ---
    bf16_t* cur = featA;
    bf16_t* nxt = featB;
    for (int i = 0; i < 4; ++i) {
        layer_fused5<<<dim3(MROWS / 16), dim3(512), 0, stream>>>(
            cur, cnt, csr, first4, cnt_pack, ovcnt, ovlist,
            wcat + (size_t)i * 15 * 16384, wctr2_b + (size_t)i * 16384,
            gn_g + i * 128, gn_b + i * 128, gn2_g + i * 128, gn2_b + i * 128,
            res_f, nxt, (i == 3) ? (float*)d_out : nullptr);
        bf16_t* tmp = cur; cur = nxt; nxt = tmp;
    }
}

// Round 11
// 458.732 us; speedup vs baseline: 1.3411x; 1.3411x over previous
//
#include <hip/hip_runtime.h>
#include <hip/hip_bf16.h>

// ---------------------------------------------------------------------------
// SparseLaneAttention on MI355X (gfx950) — round 11 (identical resubmission of
// round 10; GPU acquisition timed out, kernel never ran).
// r9 post-mortem: 8-waves-over-16-rows regressed (sync + bank conflicts, MFMA
// per wave halved). New audit: r8's blocks re-read 512KB of weights per 16
// rows -> 512MB/layer logical weight traffic (~2MB/CU), comparable to gather
// traffic. Fix: scale r8 to 32 rows / 512 threads / grid 512; wave w owns
// column w and loops both 16-row tiles REUSING weight fragments in registers
// (half the weight traffic, 2x gather ILP, same 8 MFMA/wave/type as r8).
// pO partials stored bf16 (halves flash->combine round trip).
// ---------------------------------------------------------------------------

typedef __bf16 bf16_t;
typedef __attribute__((ext_vector_type(8))) __bf16 bf16x8;
typedef __attribute__((ext_vector_type(4))) __bf16 bf16x4;
typedef __attribute__((ext_vector_type(4))) float f32x4;
typedef unsigned long long u64;

#define MROWS 16384   // B*N
#define DDIM  128
#define EEDGE 32768
#define NSEQ  1024
#define NBATCH 16
#define CAP   16
#define NTYPE 14
#define NKEY  (NTYPE * MROWS)
#define OVMAX 4096
#define NCHUNK 4      // flash KV split

// ---------------------------------------------------------------------------
// Multi-segment f32 -> bf16 conversion
// ---------------------------------------------------------------------------
struct CvtArgs {
    const float* src[6];
    bf16_t* dst[6];
    int n4[6];
};

__global__ __launch_bounds__(256) void cvt_multi(CvtArgs a, int total4) {
    int i = blockIdx.x * 256 + threadIdx.x;
    if (i >= total4) return;
    int k = 0, base = 0;
    while (i - base >= a.n4[k]) { base += a.n4[k]; ++k; }
    int j = i - base;
    float4 v = reinterpret_cast<const float4*>(a.src[k])[j];
    bf16x4 o = { (bf16_t)v.x, (bf16_t)v.y, (bf16_t)v.z, (bf16_t)v.w };
    reinterpret_cast<bf16x4*>(a.dst[k])[j] = o;
}

// ---------------------------------------------------------------------------
// wcat[layer][15][128][128] bf16; slots 0..5 pre, 6..11 suc, 12 left,
// 13 right, 14 ctr.
// ---------------------------------------------------------------------------
__global__ __launch_bounds__(256) void cvt_wcat(
    const float* __restrict__ W_ctr, const float* __restrict__ W_pre,
    const float* __restrict__ W_suc, const float* __restrict__ W_left,
    const float* __restrict__ W_right, bf16_t* __restrict__ wcat)
{
    int tid = blockIdx.x * 256 + threadIdx.x;
    int idx = tid * 4;
    if (idx >= 4 * 15 * 16384) return;
    const int PER_I = 15 * 16384;
    int i = idx / PER_I, rem = idx % PER_I;
    int slot = rem / 16384, k = rem % 16384;
    const float* src;
    if (slot < 6)       src = W_pre  + ((size_t)(i * 6 + slot) * 16384 + k);
    else if (slot < 12) src = W_suc  + ((size_t)(i * 6 + slot - 6) * 16384 + k);
    else if (slot == 12) src = W_left  + ((size_t)i * 16384 + k);
    else if (slot == 13) src = W_right + ((size_t)i * 16384 + k);
    else                 src = W_ctr   + ((size_t)i * 16384 + k);
    float4 v = *reinterpret_cast<const float4*>(src);
    bf16x4 o = { (bf16_t)v.x, (bf16_t)v.y, (bf16_t)v.z, (bf16_t)v.w };
    *reinterpret_cast<bf16x4*>(wcat + idx) = o;
}

// ---------------------------------------------------------------------------
// Build CSR (once per call; indices are call-invariant).
// ---------------------------------------------------------------------------
__global__ __launch_bounds__(256) void build_csr(
    const int* __restrict__ pre_u, const int* __restrict__ pre_v,
    const int* __restrict__ suc_u, const int* __restrict__ suc_v,
    const int* __restrict__ left_u, const int* __restrict__ left_v,
    const int* __restrict__ right_u, const int* __restrict__ right_v,
    unsigned* __restrict__ cnt, int* __restrict__ csr,
    unsigned* __restrict__ ovcnt, int* __restrict__ ovlist)
{
    int tid = blockIdx.x * 256 + threadIdx.x;
    int t = tid >> 15, e = tid & (EEDGE - 1);
    const int* ua; const int* va;
    if (t < 6)        { ua = pre_u + t * EEDGE;       va = pre_v + t * EEDGE; }
    else if (t < 12)  { ua = suc_u + (t - 6) * EEDGE; va = suc_v + (t - 6) * EEDGE; }
    else if (t == 12) { ua = left_u;  va = left_v; }
    else              { ua = right_u; va = right_v; }
    int u = ua[e], v = va[e];
    int key = t * MROWS + u;
    unsigned slot = atomicAdd(&cnt[key], 1u);
    if (slot < CAP) csr[key * CAP + slot] = v;
    else {
        unsigned o = atomicAdd(ovcnt, 1u);
        if (o < OVMAX) { ovlist[o * 2] = key; ovlist[o * 2 + 1] = v; }
    }
}

// ---------------------------------------------------------------------------
// Fused aux build: first4 (sentinel-padded) + nibble-packed per-row counts.
// ---------------------------------------------------------------------------
__global__ __launch_bounds__(256) void build_aux(
    const unsigned* __restrict__ cnt, const int* __restrict__ csr,
    int4* __restrict__ first4, u64* __restrict__ cnt_pack)
{
    int idx = blockIdx.x * 256 + threadIdx.x;
    if (idx < NKEY) {
        unsigned c = cnt[idx];
        const int* p = csr + (size_t)idx * CAP;
        int4 q;
        q.x = (c > 0) ? p[0] : MROWS;
        q.y = (c > 1) ? p[1] : MROWS;
        q.z = (c > 2) ? p[2] : MROWS;
        q.w = (c > 3) ? p[3] : MROWS;
        first4[idx] = q;
    } else if (idx < NKEY + MROWS) {
        int row = idx - NKEY;
        u64 cc = 0;
#pragma unroll
        for (int t = 0; t < NTYPE; ++t) {
            unsigned c = cnt[t * MROWS + row];
            if (c > 15u) c = 15u;
            cc |= (u64)c << (4 * t);
        }
        cnt_pack[row] = cc;
    }
}

// ---------------------------------------------------------------------------
// QKV projection; q/k outputs staged through LDS for vectorized stores.
// ---------------------------------------------------------------------------
__global__ __launch_bounds__(256) void qkv_gemm(
    const bf16_t* __restrict__ ctrs_bf, const bf16_t* __restrict__ feats_bf,
    const bf16_t* __restrict__ wq, const bf16_t* __restrict__ wk, const bf16_t* __restrict__ wv,
    bf16_t* __restrict__ q_out, bf16_t* __restrict__ k_out, bf16_t* __restrict__ vT_out)
{
    __shared__ bf16_t stg[64][132];
    const int which = blockIdx.y;
    const bf16_t* x = (which == 0) ? ctrs_bf : feats_bf;
    const bf16_t* w = (which == 0) ? wq : (which == 1) ? wk : wv;
    const int lane = threadIdx.x & 63, wave = threadIdx.x >> 6;
    const int li = lane & 15, kg = lane >> 4;
    const int row0 = blockIdx.x * 64 + wave * 16;

    bf16x8 a[4];
#pragma unroll
    for (int kk = 0; kk < 4; ++kk)
        a[kk] = *reinterpret_cast<const bf16x8*>(x + (size_t)(row0 + li) * DDIM + kk * 32 + kg * 8);

    f32x4 acc[8];
#pragma unroll
    for (int t = 0; t < 8; ++t) {
        f32x4 c = {0.f, 0.f, 0.f, 0.f};
#pragma unroll
        for (int kk = 0; kk < 4; ++kk) {
            bf16x8 b = *reinterpret_cast<const bf16x8*>(w + (size_t)(t * 16 + li) * DDIM + kk * 32 + kg * 8);
            c = __builtin_amdgcn_mfma_f32_16x16x32_bf16(a[kk], b, c, 0, 0, 0);
        }
        acc[t] = c;
    }

    if (which < 2) {
        bf16_t* out = (which == 0) ? q_out : k_out;
#pragma unroll
        for (int t = 0; t < 8; ++t) {
            int c = t * 16 + li;
#pragma unroll
            for (int r = 0; r < 4; ++r)
                stg[wave * 16 + kg * 4 + r][c] = (bf16_t)acc[t][r];
        }
        __syncthreads();
        const int rr = threadIdx.x >> 2, seg = (threadIdx.x & 3) * 32;
#pragma unroll
        for (int p = 0; p < 4; ++p) {
            bf16x8 v = *reinterpret_cast<const bf16x8*>(&stg[rr][seg + p * 8]);
            *reinterpret_cast<bf16x8*>(out + (size_t)(blockIdx.x * 64 + rr) * DDIM + seg + p * 8) = v;
        }
    } else {
        const int bb = row0 >> 10;
        const int jb = (row0 & 1023) + kg * 4;
#pragma unroll
        for (int t = 0; t < 8; ++t) {
            int c = t * 16 + li;
            bf16x4 pk = { (bf16_t)acc[t][0], (bf16_t)acc[t][1], (bf16_t)acc[t][2], (bf16_t)acc[t][3] };
            *reinterpret_cast<bf16x4*>(vT_out + ((size_t)bb * 128 + c) * NSEQ + jb) = pk;
        }
    }
}

// ---------------------------------------------------------------------------
// Flash attention, KV-split; partials pO stored bf16 (unnormalized).
// ---------------------------------------------------------------------------
__global__ __launch_bounds__(256) void flash_attn(
    const bf16_t* __restrict__ q, const bf16_t* __restrict__ k,
    const bf16_t* __restrict__ vT,
    bf16_t* __restrict__ pO, float* __restrict__ pm, float* __restrict__ pl)
{
    const int lane = threadIdx.x & 63, wave = threadIdx.x >> 6;
    const int li = lane & 15, kg = lane >> 4;
    const int b = blockIdx.y;
    const int chunk = blockIdx.z;
    const int i0 = blockIdx.x * 64 + wave * 16;

    __shared__ bf16_t p_lds[4][16][48];

    bf16x8 qf[4];
#pragma unroll
    for (int kk = 0; kk < 4; ++kk)
        qf[kk] = *reinterpret_cast<const bf16x8*>(q + ((size_t)b * NSEQ + i0 + li) * DDIM + kk * 32 + kg * 8);

    float m_run = -1e30f, l_run = 0.f;
    f32x4 o[8];
#pragma unroll
    for (int t = 0; t < 8; ++t) o[t] = f32x4{0.f, 0.f, 0.f, 0.f};

    const float nf = 0.08838834764831845f;
    const int jlo = chunk * (NSEQ / NCHUNK), jhi = jlo + NSEQ / NCHUNK;

    for (int j0 = jlo; j0 < jhi; j0 += 32) {
        f32x4 s[2];
#pragma unroll
        for (int sub = 0; sub < 2; ++sub) {
            f32x4 c = {0.f, 0.f, 0.f, 0.f};
#pragma unroll
            for (int kk = 0; kk < 4; ++kk) {
                bf16x8 a = *reinterpret_cast<const bf16x8*>(
                    k + ((size_t)b * NSEQ + j0 + sub * 16 + li) * DDIM + kk * 32 + kg * 8);
                c = __builtin_amdgcn_mfma_f32_16x16x32_bf16(a, qf[kk], c, 0, 0, 0);
            }
            s[sub] = c;
        }
        float smax = -1e30f;
#pragma unroll
        for (int sub = 0; sub < 2; ++sub)
#pragma unroll
            for (int r = 0; r < 4; ++r) { s[sub][r] *= nf; smax = fmaxf(smax, s[sub][r]); }
        smax = fmaxf(smax, __shfl_xor(smax, 16));
        smax = fmaxf(smax, __shfl_xor(smax, 32));
        float m_new = fmaxf(m_run, smax);
        float alpha = __expf(m_run - m_new);
        float psum = 0.f;
#pragma unroll
        for (int sub = 0; sub < 2; ++sub) {
            bf16x4 pk;
#pragma unroll
            for (int r = 0; r < 4; ++r) {
                float p = __expf(s[sub][r] - m_new);
                psum += p;
                pk[r] = (bf16_t)p;
            }
            *reinterpret_cast<bf16x4*>(&p_lds[wave][li][sub * 16 + kg * 4]) = pk;
        }
        psum += __shfl_xor(psum, 16);
        psum += __shfl_xor(psum, 32);
        l_run = l_run * alpha + psum;
        m_run = m_new;

        float al[4];
#pragma unroll
        for (int r = 0; r < 4; ++r) al[r] = __shfl(alpha, kg * 4 + r);

        asm volatile("s_waitcnt lgkmcnt(0)" ::: "memory");
        __builtin_amdgcn_sched_barrier(0);

        bf16x8 pa = *reinterpret_cast<const bf16x8*>(&p_lds[wave][li][kg * 8]);

#pragma unroll
        for (int t = 0; t < 8; ++t)
#pragma unroll
            for (int r = 0; r < 4; ++r) o[t][r] *= al[r];

#pragma unroll
        for (int t = 0; t < 8; ++t) {
            bf16x8 vb = *reinterpret_cast<const bf16x8*>(
                vT + ((size_t)b * 128 + t * 16 + li) * NSEQ + j0 + kg * 8);
            o[t] = __builtin_amdgcn_mfma_f32_16x16x32_bf16(pa, vb, o[t], 0, 0, 0);
        }
    }

#pragma unroll
    for (int t = 0; t < 8; ++t) {
        int c = t * 16 + li;
#pragma unroll
        for (int r = 0; r < 4; ++r) {
            size_t m = (size_t)b * NSEQ + i0 + kg * 4 + r;
            pO[((size_t)chunk * MROWS + m) * DDIM + c] = (bf16_t)o[t][r];
        }
    }
    float m_r[4], l_r[4];
#pragma unroll
    for (int r = 0; r < 4; ++r) { m_r[r] = __shfl(m_run, kg * 4 + r); l_r[r] = __shfl(l_run, kg * 4 + r); }
    if (li == 0) {
#pragma unroll
        for (int r = 0; r < 4; ++r) {
            size_t m = (size_t)b * NSEQ + i0 + kg * 4 + r;
            pm[(size_t)chunk * MROWS + m] = m_r[r];
            pl[(size_t)chunk * MROWS + m] = l_r[r];
        }
    }
}

// ---------------------------------------------------------------------------
// Combine chunk partials (exact) -> feat = feats + att.
// ---------------------------------------------------------------------------
__global__ __launch_bounds__(256) void attn_combine(
    const bf16_t* __restrict__ pO, const float* __restrict__ pm, const float* __restrict__ pl,
    const float* __restrict__ feats, bf16_t* __restrict__ feat_bf, float* __restrict__ res)
{
    int idx = blockIdx.x * 256 + threadIdx.x;
    int row = idx >> 7;
    float mx = -1e30f;
#pragma unroll
    for (int c = 0; c < NCHUNK; ++c) mx = fmaxf(mx, pm[(size_t)c * MROWS + row]);
    float num = 0.f, den = 0.f;
#pragma unroll
    for (int c = 0; c < NCHUNK; ++c) {
        float wgt = __expf(pm[(size_t)c * MROWS + row] - mx);
        den += wgt * pl[(size_t)c * MROWS + row];
        num += wgt * (float)pO[((size_t)c * MROWS + row) * DDIM + (idx & 127)];
    }
    float f = feats[idx] + num / den;
    feat_bf[idx] = (bf16_t)f;
    res[idx] = f;
}

// ---------------------------------------------------------------------------
// Fused layer kernel v6.  Block = 32 dest rows, 512 threads (8 waves), 43KB.
// Gather: thread (r=tid>>4, lp=tid&15) owns (row, 8ch); one type per
// iteration for all 32 rows (2x r8's loads in flight), double-buffered slab.
// MFMA: wave w owns column-block w; loops both 16-row tiles REUSING the
// weight fragments in registers (halves weight traffic per output row).
// Tail: GN1+ReLU -> ctr2 MFMA (same reuse) -> GN2 + residual + ReLU.
// ---------------------------------------------------------------------------
__global__ __launch_bounds__(512) void layer_fused6(
    const bf16_t* __restrict__ fin,          // (MROWS+1) rows; row MROWS = 0
    const unsigned* __restrict__ cnt, const int* __restrict__ csr,
    const int4* __restrict__ first4, const u64* __restrict__ cnt_pack,
    const unsigned* __restrict__ ovcnt, const int* __restrict__ ovlist,
    const bf16_t* __restrict__ wcat_l, const bf16_t* __restrict__ wctr2_l,
    const float* __restrict__ g1, const float* __restrict__ b1,
    const float* __restrict__ g2, const float* __restrict__ b2,
    float* __restrict__ res, bf16_t* __restrict__ fout, float* __restrict__ out_f32)
{
    __shared__ bf16_t slab[2][32][136];   // 17408 B
    __shared__ float  t2[32][132];        // 16896 B
    __shared__ bf16_t yA[32][136];        // 8704 B
    const int tid = threadIdx.x;
    const int r = tid >> 4, lp = tid & 15;       // r in 0..31
    const int row0 = blockIdx.x * 32;
    const int row = row0 + r;
    const int ch = lp * 8;
    const int lane = tid & 63, w = tid >> 6;     // wave 0..7 = column block
    const int li = lane & 15, kg = lane >> 4;

    const u64 cc = cnt_pack[row];

    auto gather_t = [&](int t, float* s) {
        int4 qd = first4[t * MROWS + row];
        bf16x8 x0 = *reinterpret_cast<const bf16x8*>(fin + (size_t)qd.x * DDIM + ch);
        bf16x8 x1 = *reinterpret_cast<const bf16x8*>(fin + (size_t)qd.y * DDIM + ch);
        bf16x8 x2 = *reinterpret_cast<const bf16x8*>(fin + (size_t)qd.z * DDIM + ch);
        bf16x8 x3 = *reinterpret_cast<const bf16x8*>(fin + (size_t)qd.w * DDIM + ch);
#pragma unroll
        for (int z = 0; z < 8; ++z)
            s[z] = ((float)x0[z] + (float)x1[z]) + ((float)x2[z] + (float)x3[z]);
        int nib = (int)((cc >> (4 * t)) & 15u);
        if (nib > 4) {                                   // rare
            const int key = t * MROWS + row;
            unsigned craw = (nib == 15) ? cnt[key] : (unsigned)nib;
            int c = (int)(craw < CAP ? craw : CAP);
            for (int j = 4; j < c; ++j) {
                bf16x8 x = *reinterpret_cast<const bf16x8*>(fin + (size_t)csr[(size_t)key * CAP + j] * DDIM + ch);
#pragma unroll
                for (int z = 0; z < 8; ++z) s[z] += (float)x[z];
            }
            if (craw > CAP) {                            // ~never
                unsigned no = *ovcnt; if (no > OVMAX) no = OVMAX;
                for (unsigned o = 0; o < no; ++o) {
                    if (ovlist[o * 2] == key) {
                        bf16x8 x = *reinterpret_cast<const bf16x8*>(fin + (size_t)ovlist[o * 2 + 1] * DDIM + ch);
#pragma unroll
                        for (int z = 0; z < 8; ++z) s[z] += (float)x[z];
                    }
                }
            }
        }
    };

    f32x4 acc[2];                                 // row-tile 0/1, column block w
    acc[0] = f32x4{0.f, 0.f, 0.f, 0.f};
    acc[1] = f32x4{0.f, 0.f, 0.f, 0.f};

    // prologue: gather type 0 -> slab[0]; ctr slot (14) MFMA from fin meanwhile
    {
        float s[8];
        gather_t(0, s);
        const bf16_t* wt = wcat_l + (size_t)14 * 16384;
#pragma unroll
        for (int kk = 0; kk < 4; ++kk) {
            bf16x8 b = *reinterpret_cast<const bf16x8*>(wt + (size_t)(w * 16 + li) * DDIM + kk * 32 + kg * 8);
            bf16x8 a0 = *reinterpret_cast<const bf16x8*>(fin + (size_t)(row0 + li) * DDIM + kk * 32 + kg * 8);
            acc[0] = __builtin_amdgcn_mfma_f32_16x16x32_bf16(a0, b, acc[0], 0, 0, 0);
            bf16x8 a1 = *reinterpret_cast<const bf16x8*>(fin + (size_t)(row0 + 16 + li) * DDIM + kk * 32 + kg * 8);
            acc[1] = __builtin_amdgcn_mfma_f32_16x16x32_bf16(a1, b, acc[1], 0, 0, 0);
        }
        bf16x8 av;
#pragma unroll
        for (int z = 0; z < 8; ++z) av[z] = (bf16_t)s[z];
        *reinterpret_cast<bf16x8*>(&slab[0][r][ch]) = av;
    }
    __syncthreads();

    for (int t = 0; t < NTYPE; ++t) {
        float s2[8];
        const bool more = (t < NTYPE - 1);
        if (more) gather_t(t + 1, s2);               // overlaps MFMA below

        const bf16_t* wt = wcat_l + (size_t)t * 16384;
        const int sb = t & 1;
#pragma unroll
        for (int kk = 0; kk < 4; ++kk) {
            bf16x8 b = *reinterpret_cast<const bf16x8*>(wt + (size_t)(w * 16 + li) * DDIM + kk * 32 + kg * 8);
            bf16x8 a0 = *reinterpret_cast<const bf16x8*>(&slab[sb][li][kk * 32 + kg * 8]);
            acc[0] = __builtin_amdgcn_mfma_f32_16x16x32_bf16(a0, b, acc[0], 0, 0, 0);
            bf16x8 a1 = *reinterpret_cast<const bf16x8*>(&slab[sb][16 + li][kk * 32 + kg * 8]);
            acc[1] = __builtin_amdgcn_mfma_f32_16x16x32_bf16(a1, b, acc[1], 0, 0, 0);
        }

        if (more) {
            bf16x8 av;
#pragma unroll
            for (int z = 0; z < 8; ++z) av[z] = (bf16_t)s2[z];
            *reinterpret_cast<bf16x8*>(&slab[sb ^ 1][r][ch]) = av;
        }
        __syncthreads();
    }

#pragma unroll
    for (int rt = 0; rt < 2; ++rt)
#pragma unroll
        for (int rr = 0; rr < 4; ++rr)
            t2[rt * 16 + kg * 4 + rr][w * 16 + li] = acc[rt][rr];
    __syncthreads();

    // ---- GN1 + ReLU -> yA (thread (r,lp), all 512 active) ----
    {
        float s[8];
#pragma unroll
        for (int z = 0; z < 8; ++z) s[z] = t2[r][ch + z];
        float sm = 0.f, sq = 0.f;
#pragma unroll
        for (int z = 0; z < 8; ++z) { sm += s[z]; sq += s[z] * s[z]; }
#pragma unroll
        for (int off = 1; off < 16; off <<= 1) { sm += __shfl_xor(sm, off); sq += __shfl_xor(sq, off); }
        float mu = sm * (1.f / 128.f);
        float var = sq * (1.f / 128.f) - mu * mu;
        float rstd = rsqrtf(var + 1e-5f);
        bf16x8 yv;
#pragma unroll
        for (int z = 0; z < 8; ++z) {
            float y = fmaxf((s[z] - mu) * rstd * g1[ch + z] + b1[ch + z], 0.f);
            yv[z] = (bf16_t)y;
        }
        *reinterpret_cast<bf16x8*>(&yA[r][ch]) = yv;
    }
    __syncthreads();

    // ---- ctr2 GEMM from yA (wave w = col block w, both row tiles) ----
    {
        f32x4 c2[2];
        c2[0] = f32x4{0.f, 0.f, 0.f, 0.f};
        c2[1] = f32x4{0.f, 0.f, 0.f, 0.f};
#pragma unroll
        for (int kk = 0; kk < 4; ++kk) {
            bf16x8 b = *reinterpret_cast<const bf16x8*>(wctr2_l + (size_t)(w * 16 + li) * DDIM + kk * 32 + kg * 8);
            bf16x8 a0 = *reinterpret_cast<const bf16x8*>(&yA[li][kk * 32 + kg * 8]);
            c2[0] = __builtin_amdgcn_mfma_f32_16x16x32_bf16(a0, b, c2[0], 0, 0, 0);
            bf16x8 a1 = *reinterpret_cast<const bf16x8*>(&yA[16 + li][kk * 32 + kg * 8]);
            c2[1] = __builtin_amdgcn_mfma_f32_16x16x32_bf16(a1, b, c2[1], 0, 0, 0);
        }
        __syncthreads();
#pragma unroll
        for (int rt = 0; rt < 2; ++rt)
#pragma unroll
            for (int rr = 0; rr < 4; ++rr)
                t2[rt * 16 + kg * 4 + rr][w * 16 + li] = c2[rt][rr];
    }
    __syncthreads();

    // ---- GN2 + residual + ReLU ----
    {
        float v[8];
#pragma unroll
        for (int z = 0; z < 8; ++z) v[z] = t2[r][ch + z];
        float sm = 0.f, sq = 0.f;
#pragma unroll
        for (int z = 0; z < 8; ++z) { sm += v[z]; sq += v[z] * v[z]; }
#pragma unroll
        for (int off = 1; off < 16; off <<= 1) { sm += __shfl_xor(sm, off); sq += __shfl_xor(sq, off); }
        float mu = sm * (1.f / 128.f);
        float var = sq * (1.f / 128.f) - mu * mu;
        float rstd = rsqrtf(var + 1e-5f);

        size_t base = (size_t)row * DDIM + ch;
        float rv[8];
        *reinterpret_cast<float4*>(&rv[0]) = *reinterpret_cast<const float4*>(res + base);
        *reinterpret_cast<float4*>(&rv[4]) = *reinterpret_cast<const float4*>(res + base + 4);
        bf16x8 fo;
#pragma unroll
        for (int z = 0; z < 8; ++z) {
            float y = (v[z] - mu) * rstd * g2[ch + z] + b2[ch + z];
            float f = fmaxf(y + rv[z], 0.f);
            rv[z] = f;
            fo[z] = (bf16_t)f;
        }
        *reinterpret_cast<float4*>(res + base) = *reinterpret_cast<float4*>(&rv[0]);
        *reinterpret_cast<float4*>(res + base + 4) = *reinterpret_cast<float4*>(&rv[4]);
        *reinterpret_cast<bf16x8*>(fout + base) = fo;
        if (out_f32) {
            *reinterpret_cast<float4*>(out_f32 + base) = *reinterpret_cast<float4*>(&rv[0]);
            *reinterpret_cast<float4*>(out_f32 + base + 4) = *reinterpret_cast<float4*>(&rv[4]);
        }
    }
}

// ---------------------------------------------------------------------------
// Host launch
// ---------------------------------------------------------------------------
extern "C" void kernel_launch(void* const* d_in, const int* in_sizes, int n_in,
                              void* d_out, int out_size, void* d_ws, size_t ws_size,
                              hipStream_t stream) {
    const float* ctrs   = (const float*)d_in[0];
    const float* feats  = (const float*)d_in[1];
    const float* Wq     = (const float*)d_in[2];
    const float* Wk     = (const float*)d_in[3];
    const float* Wv     = (const float*)d_in[4];
    const float* W_ctr  = (const float*)d_in[5];
    const float* W_pre  = (const float*)d_in[6];
    const float* W_suc  = (const float*)d_in[7];
    const float* W_left = (const float*)d_in[8];
    const float* W_right= (const float*)d_in[9];
    const float* W_ctr2 = (const float*)d_in[10];
    const float* gn_g   = (const float*)d_in[11];
    const float* gn_b   = (const float*)d_in[12];
    const float* gn2_g  = (const float*)d_in[13];
    const float* gn2_b  = (const float*)d_in[14];
    const int* pre_u    = (const int*)d_in[15];
    const int* pre_v    = (const int*)d_in[16];
    const int* suc_u    = (const int*)d_in[17];
    const int* suc_v    = (const int*)d_in[18];
    const int* left_u   = (const int*)d_in[19];
    const int* left_v   = (const int*)d_in[20];
    const int* right_u  = (const int*)d_in[21];
    const int* right_v  = (const int*)d_in[22];
    (void)in_sizes; (void)n_in; (void)out_size; (void)ws_size;

    size_t off = 0;
    auto alloc = [&](size_t bytes) -> void* {
        void* p = (char*)d_ws + off;
        off += (bytes + 255) & ~(size_t)255;
        return p;
    };
    // persistent region
    bf16_t* wq_b    = (bf16_t*)alloc(16384 * 2);
    bf16_t* wk_b    = (bf16_t*)alloc(16384 * 2);
    bf16_t* wv_b    = (bf16_t*)alloc(16384 * 2);
    bf16_t* wctr2_b = (bf16_t*)alloc(65536 * 2);
    bf16_t* wcat    = (bf16_t*)alloc((size_t)4 * 15 * 16384 * 2);
    bf16_t* featA   = (bf16_t*)alloc((size_t)(MROWS + 1) * DDIM * 2);   // +1 zero row
    bf16_t* featB   = (bf16_t*)alloc((size_t)(MROWS + 1) * DDIM * 2);   // +1 zero row
    float*  res_f   = (float*)alloc((size_t)MROWS * DDIM * 4);
    unsigned* cnt   = (unsigned*)alloc((size_t)NKEY * 4);
    unsigned* ovcnt = (unsigned*)alloc(256);
    int*    csr     = (int*)alloc((size_t)NKEY * CAP * 4);
    int*    ovlist  = (int*)alloc((size_t)OVMAX * 2 * 4);
    int4*   first4  = (int4*)alloc((size_t)NKEY * 16);
    u64*    cnt_pack= (u64*)alloc((size_t)MROWS * 8);

    // attention-phase temporaries
    bf16_t* ctrs_b  = (bf16_t*)alloc((size_t)MROWS * DDIM * 2);
    bf16_t* feats_b = (bf16_t*)alloc((size_t)MROWS * DDIM * 2);
    bf16_t* q_b     = (bf16_t*)alloc((size_t)MROWS * DDIM * 2);
    bf16_t* k_b     = (bf16_t*)alloc((size_t)MROWS * DDIM * 2);
    bf16_t* vT_b    = (bf16_t*)alloc((size_t)MROWS * DDIM * 2);
    float*  pm      = (float*)alloc((size_t)NCHUNK * MROWS * 4);
    float*  pl      = (float*)alloc((size_t)NCHUNK * MROWS * 4);
    bf16_t* pO      = (bf16_t*)alloc((size_t)NCHUNK * MROWS * DDIM * 2);

    // --- preprocessing ---
    hipMemsetAsync(cnt, 0, (size_t)NKEY * 4 + 256, stream);            // cnt + ovcnt
    hipMemsetAsync(featA + (size_t)MROWS * DDIM, 0, DDIM * 2, stream); // zero sentinel rows
    hipMemsetAsync(featB + (size_t)MROWS * DDIM, 0, DDIM * 2, stream);

    CvtArgs ca;
    ca.src[0] = ctrs;   ca.dst[0] = ctrs_b;  ca.n4[0] = MROWS * DDIM / 4;
    ca.src[1] = feats;  ca.dst[1] = feats_b; ca.n4[1] = MROWS * DDIM / 4;
    ca.src[2] = Wq;     ca.dst[2] = wq_b;    ca.n4[2] = 16384 / 4;
    ca.src[3] = Wk;     ca.dst[3] = wk_b;    ca.n4[3] = 16384 / 4;
    ca.src[4] = Wv;     ca.dst[4] = wv_b;    ca.n4[4] = 16384 / 4;
    ca.src[5] = W_ctr2; ca.dst[5] = wctr2_b; ca.n4[5] = 65536 / 4;
    int total4 = (2 * MROWS * DDIM + 3 * 16384 + 65536) / 4;
    cvt_multi<<<dim3((total4 + 255) / 256), dim3(256), 0, stream>>>(ca, total4);

    cvt_wcat<<<dim3((4 * 15 * 16384 / 4 + 255) / 256), dim3(256), 0, stream>>>(
        W_ctr, W_pre, W_suc, W_left, W_right, wcat);

    build_csr<<<dim3(NTYPE * EEDGE / 256), dim3(256), 0, stream>>>(
        pre_u, pre_v, suc_u, suc_v, left_u, left_v, right_u, right_v,
        cnt, csr, ovcnt, ovlist);

    build_aux<<<dim3((NKEY + MROWS + 255) / 256), dim3(256), 0, stream>>>(
        cnt, csr, first4, cnt_pack);

    // --- attention ---
    qkv_gemm<<<dim3(MROWS / 64, 3), dim3(256), 0, stream>>>(
        ctrs_b, feats_b, wq_b, wk_b, wv_b, q_b, k_b, vT_b);

    flash_attn<<<dim3(NSEQ / 64, NBATCH, NCHUNK), dim3(256), 0, stream>>>(
        q_b, k_b, vT_b, pO, pm, pl);

    attn_combine<<<dim3(MROWS * DDIM / 256), dim3(256), 0, stream>>>(
        pO, pm, pl, feats, featA, res_f);

    // --- fusion layers ---
    bf16_t* cur = featA;
    bf16_t* nxt = featB;
    for (int i = 0; i < 4; ++i) {
        layer_fused6<<<dim3(MROWS / 32), dim3(512), 0, stream>>>(
            cur, cnt, csr, first4, cnt_pack, ovcnt, ovlist,
            wcat + (size_t)i * 15 * 16384, wctr2_b + (size_t)i * 16384,
            gn_g + i * 128, gn_b + i * 128, gn2_g + i * 128, gn2_b + i * 128,
            res_f, nxt, (i == 3) ? (float*)d_out : nullptr);
        bf16_t* tmp = cur; cur = nxt; nxt = tmp;
    }
}